// Round 17
// baseline (166.231 us; speedup 1.0000x reference)
//
#include <hip/hip_runtime.h>
#include <math.h>

#define BB 8
#define NP 2048
#define NAA 512
#define KNN 16
#define KK2 14
#define DE 16
#define NG 64
#define FF 128
#define FF2 128
#define NCAT 39
#define EPSV 1e-6f

typedef __attribute__((ext_vector_type(8))) short bf16x8;
typedef __attribute__((ext_vector_type(4))) float f32x4;

// round-to-nearest-even f32 -> bf16 value (kept in f32)
__device__ __forceinline__ float bf16r(float x) {
    unsigned u = __float_as_uint(x);
    u = u + 0x7FFFu + ((u >> 16) & 1u);
    return __uint_as_float(u & 0xFFFF0000u);
}
__device__ __forceinline__ unsigned short bf16u(float x) {
    unsigned u = __float_as_uint(x);
    u = u + 0x7FFFu + ((u >> 16) & 1u);
    return (unsigned short)(u >> 16);
}

// ---------------- workspace layout (bytes) ----------------
#define OFF_CENTER   0u
#define OFF_R        262144u
#define OFF_ATTR     1048576u
#define OFF_NBR      2097152u
#define OFF_ATT      3145728u
#define OFF_FEAT     3211264u
#define OFF_POOLED   11599872u
#define OFF_WFFRAG   (OFF_POOLED)
#define OFF_WFEATFRAG (OFF_POOLED + 262144u)
#define OFF_START    13697024u
#define OFF_PARTS    13713536u
#define OFF_PARTQ    13746304u
#define OFF_SS       13779072u

// ================= K0: pack W_filter / W_feat into MFMA B-fragment order ===
__global__ __launch_bounds__(256) void k_prep(
    const float* __restrict__ Wf, const float* __restrict__ Wfeat,
    unsigned short* __restrict__ WfF, unsigned short* __restrict__ WfeatF)
{
    int id = blockIdx.x * 256 + threadIdx.x;
    if (id < 32*8*64*8) {
        int i = id & 7, l = (id >> 3) & 63, nt = (id >> 9) & 7, s = id >> 12;
        int row = s*32 + (l >> 4)*8 + i;
        int col = nt*16 + (l & 15);
        WfF[id] = bf16u(Wf[(size_t)row*FF + col]);
    } else {
        int id2 = id - 32*8*64*8;
        if (id2 < 4*8*64*8) {
            int i = id2 & 7, l = (id2 >> 3) & 63, nt = (id2 >> 9) & 7, s = id2 >> 12;
            int row = s*32 + (l >> 4)*8 + i;
            int col = nt*16 + (l & 15);
            WfeatF[id2] = bf16u(Wfeat[(size_t)row*FF2 + col]);
        }
    }
}

// ================= K1: frames + attr (identical) =================
__global__ __launch_bounds__(256) void k_frames(
    const int* __restrict__ fidx, const int* __restrict__ aidx,
    const float* __restrict__ pc, const float* __restrict__ mframe,
    const float* __restrict__ emb,
    float* __restrict__ center4, float* __restrict__ R12, float* __restrict__ attr16)
{
    int t = blockIdx.x * 256 + threadIdx.x;
    if (t >= BB * NP) return;
    int b = t / NP;
    const float* pcb = pc + (size_t)b * NP * 3;
    int i0 = fidx[t*3+0], i1 = fidx[t*3+1], i2 = fidx[t*3+2];
    float cx = pcb[i0*3+0], cy = pcb[i0*3+1], cz = pcb[i0*3+2];
    float ax = pcb[i1*3+0]-cx, ay = pcb[i1*3+1]-cy, az = pcb[i1*3+2]-cz;
    float bx = pcb[i2*3+0]-cx, by = pcb[i2*3+1]-cy, bz = pcb[i2*3+2]-cz;
    float n1 = sqrtf(ax*ax + ay*ay + az*az) + EPSV;
    float e1x = ax/n1, e1y = ay/n1, e1z = az/n1;
    float nx = ay*bz - az*by;
    float ny = az*bx - ax*bz;
    float nz = ax*by - ay*bx;
    float n3 = sqrtf(nx*nx + ny*ny + nz*nz) + EPSV;
    float e3x = nx/n3, e3y = ny/n3, e3z = nz/n3;
    float e2x = e3y*e1z - e3z*e1y;
    float e2y = e3z*e1x - e3x*e1z;
    float e2z = e3x*e1y - e3y*e1x;

    float4 c4; c4.x = cx; c4.y = cy; c4.z = cz; c4.w = 0.f;
    *(float4*)(center4 + (size_t)t*4) = c4;
    float* Rp = R12 + (size_t)t*12;
    Rp[0]=bf16r(e1x); Rp[1]=bf16r(e1y); Rp[2]=bf16r(e1z);
    Rp[3]=bf16r(e2x); Rp[4]=bf16r(e2y); Rp[5]=bf16r(e2z);
    Rp[6]=bf16r(e3x); Rp[7]=bf16r(e3y); Rp[8]=bf16r(e3z);

    int ai = aidx[t];
    float m = mframe[t];
    const float* er = emb + (size_t)ai * DE;
    float* ap = attr16 + (size_t)t * DE;
    #pragma unroll
    for (int d = 0; d < DE; ++d) ap[d] = bf16r(er[d] * m);
}

// ================= K2: KNN top-16 — L2-resident scan, tiny LDS ============
// 2048 blocks x 256 thr: 8 queries x 32 splits x 64 candidates. Candidate
// coords read directly from center4 (L2-resident, 1 dwordx4/cand, broadcast
// within 8-lane split group). Pass A: 4 independent 2-deep value chains per
// lane (elements of each 4-candidate group); kept = 32sp x 4ch x 2 = 256
// values/query; T' = 16th of kept >= true 16th (subset property). Pass B:
// gather {j : d2 <= T'}; final exact (d2,idx) sort -> bit-identical.
__global__ __launch_bounds__(256) void k_knn(
    const float* __restrict__ center4, int* __restrict__ nbr)
{
    __shared__ unsigned long long lists[8*128];      // 8192 B (aliased w/ kbufA)
    __shared__ int cntS[8];
    __shared__ unsigned int TqU[8];
    unsigned int* kbufA = (unsigned int*)lists;      // [8][256]

    int b = blockIdx.x >> 8;
    int qchunk = blockIdx.x & 255;
    int t = threadIdx.x;
    int qloc = t & 7, split = t >> 3;                // 8 q x 32 splits x 64 cand
    int q = qchunk * 8 + qloc;
    const float4* cb4 = (const float4*)(center4 + (size_t)b * NP * 4);
    float4 qc = cb4[q];
    float qx = qc.x, qy = qc.y, qz = qc.z;
    int j0 = split * 64;

    // ---- pass A: 4 independent 2-deep chains (elements 0..3 of each group)
    unsigned int e0a = ~0u, e1a = ~0u;
    unsigned int e0b = ~0u, e1b = ~0u;
    unsigned int e0c = ~0u, e1c = ~0u;
    unsigned int e0d = ~0u, e1d = ~0u;
    for (int jj = 0; jj < 64; jj += 4) {
        int j = j0 + jj;
        float4 p0 = cb4[j+0];
        float4 p1 = cb4[j+1];
        float4 p2 = cb4[j+2];
        float4 p3 = cb4[j+3];
        float dx0 = __fsub_rn(qx, p0.x), dy0 = __fsub_rn(qy, p0.y), dz0 = __fsub_rn(qz, p0.z);
        float dx1 = __fsub_rn(qx, p1.x), dy1 = __fsub_rn(qy, p1.y), dz1 = __fsub_rn(qz, p1.z);
        float dx2 = __fsub_rn(qx, p2.x), dy2 = __fsub_rn(qy, p2.y), dz2 = __fsub_rn(qz, p2.z);
        float dx3 = __fsub_rn(qx, p3.x), dy3 = __fsub_rn(qy, p3.y), dz3 = __fsub_rn(qz, p3.z);
        unsigned c0 = __float_as_uint(__fadd_rn(__fadd_rn(__fmul_rn(dx0,dx0), __fmul_rn(dy0,dy0)), __fmul_rn(dz0,dz0)));
        unsigned c1 = __float_as_uint(__fadd_rn(__fadd_rn(__fmul_rn(dx1,dx1), __fmul_rn(dy1,dy1)), __fmul_rn(dz1,dz1)));
        unsigned c2 = __float_as_uint(__fadd_rn(__fadd_rn(__fmul_rn(dx2,dx2), __fmul_rn(dy2,dy2)), __fmul_rn(dz2,dz2)));
        unsigned c3 = __float_as_uint(__fadd_rn(__fadd_rn(__fmul_rn(dx3,dx3), __fmul_rn(dy3,dy3)), __fmul_rn(dz3,dz3)));
        unsigned n1;
        n1 = max(e0a, min(e1a, c0)); e0a = min(e0a, c0); e1a = n1;
        n1 = max(e0b, min(e1b, c1)); e0b = min(e0b, c1); e1b = n1;
        n1 = max(e0c, min(e1c, c2)); e0c = min(e0c, c2); e1c = n1;
        n1 = max(e0d, min(e1d, c3)); e0d = min(e0d, c3); e1d = n1;
    }
    kbufA[0*256 + t] = e0a;
    kbufA[1*256 + t] = e1a;
    kbufA[2*256 + t] = e0b;
    kbufA[3*256 + t] = e1b;
    kbufA[4*256 + t] = e0c;
    kbufA[5*256 + t] = e1c;
    kbufA[6*256 + t] = e0d;
    kbufA[7*256 + t] = e1d;
    __syncthreads();

    // ---- merge: T' = 16th smallest of 32 splits x 4 chains x 2 kept
    if (t < 8) {
        unsigned int arr[16];
        #pragma unroll
        for (int s = 0; s < 16; ++s) arr[s] = ~0u;
        for (int sp = 0; sp < 32; ++sp) {
            int lidx = sp*8 + t;
            #pragma unroll
            for (int ch = 0; ch < 4; ++ch) {
                #pragma unroll
                for (int s = 0; s < 2; ++s) {
                    unsigned int v = kbufA[(ch*2 + s)*256 + lidx];
                    if (v >= arr[15]) break;         // chain pair sorted asc
                    unsigned int c = v;
                    #pragma unroll
                    for (int u = 0; u < 16; ++u) {
                        unsigned int lo = min(c, arr[u]), hi = max(c, arr[u]);
                        arr[u] = lo; c = hi;
                    }
                }
            }
        }
        TqU[t] = arr[15];
        cntS[t] = 0;
    }
    __syncthreads();       // merge done -> kbufA dead -> lists reuse OK
    unsigned int T = TqU[qloc];

    // ---- pass B: gather all candidates with d2 <= T' (exact formula)
    for (int jj = 0; jj < 64; jj += 4) {
        int j = j0 + jj;
        float4 p0 = cb4[j+0];
        float4 p1 = cb4[j+1];
        float4 p2 = cb4[j+2];
        float4 p3 = cb4[j+3];
        #pragma unroll
        for (int c4i = 0; c4i < 4; ++c4i) {
            float xx = c4i==0?p0.x:c4i==1?p1.x:c4i==2?p2.x:p3.x;
            float yy = c4i==0?p0.y:c4i==1?p1.y:c4i==2?p2.y:p3.y;
            float zz = c4i==0?p0.z:c4i==1?p1.z:c4i==2?p2.z:p3.z;
            float dx = __fsub_rn(qx, xx);
            float dy = __fsub_rn(qy, yy);
            float dz = __fsub_rn(qz, zz);
            float d2 = __fadd_rn(__fadd_rn(__fmul_rn(dx,dx), __fmul_rn(dy,dy)), __fmul_rn(dz,dz));
            unsigned int db = __float_as_uint(d2);
            if (db <= T) {
                int slot = atomicAdd(&cntS[qloc], 1);
                if (slot < 126)
                    lists[qloc*128 + slot] = ((unsigned long long)db << 32) | (unsigned)(j + c4i);
            }
        }
    }
    __syncthreads();

    // ---- final: exact (d2, idx) top-16 of gathered (lower-index ties)
    if (t < 8) {
        int n = cntS[t] < 126 ? cntS[t] : 126;
        unsigned long long arr[16];
        #pragma unroll
        for (int s = 0; s < 16; ++s) arr[s] = ~0ULL;
        for (int i = 0; i < n; ++i) {
            unsigned long long key = lists[t*128 + i];
            if (key < arr[15]) {
                unsigned long long c = key;
                #pragma unroll
                for (int u = 0; u < 16; ++u) {
                    unsigned long long lo = c < arr[u] ? c : arr[u];
                    unsigned long long hi = c < arr[u] ? arr[u] : c;
                    arr[u] = lo; c = hi;
                }
            }
        }
        int qg = qchunk * 8 + t;
        int* outp = nbr + ((size_t)b*NP + qg) * KNN;
        #pragma unroll
        for (int s = 0; s < 16; ++s) outp[s] = (int)(arr[s] & 0xFFFFFFFFu);
    }
}

// ================= K3: gauss filter + MFMA y/feat (identical) =======
__global__ __launch_bounds__(256) void k_filter(
    const float* __restrict__ center4, const float* __restrict__ R12,
    const float* __restrict__ attr16, const int* __restrict__ nbr,
    const float* __restrict__ mframe,
    const float* __restrict__ mu, const float* __restrict__ sigma,
    const unsigned short* __restrict__ WfF, const float* __restrict__ Watt,
    const unsigned short* __restrict__ WfeatF,
    float* __restrict__ att, float* __restrict__ feat)
{
    __shared__ float cG[NG*8];
    __shared__ float locS[256*5];
    __shared__ float gaussS[256*17];
    __shared__ __align__(16) unsigned short ZsU[16*256];
    __shared__ __align__(16) unsigned short yU[16*128];
    __shared__ float cS[16*4];
    __shared__ float RS[16*12];
    __shared__ int   nbrS[256];
    __shared__ float mfS[16];

    int t = threadIdx.x;
    int lane = t & 63, w = t >> 6;
    int blk = blockIdx.x;
    int b = blk / (NP/16);
    int abase = (blk % (NP/16)) * 16;
    size_t gbase = (size_t)b * NP + abase;

    if (t < NG) {
        float s0 = sigma[t*3+0], s1 = sigma[t*3+1], s2 = sigma[t*3+2];
        float i0 = 1.f/(s0*s0 + EPSV), i1 = 1.f/(s1*s1 + EPSV), i2 = 1.f/(s2*s2 + EPSV);
        float m0 = mu[t*3+0], m1 = mu[t*3+1], m2 = mu[t*3+2];
        float* cg = cG + t*8;
        cg[0]=bf16r(i0); cg[1]=bf16r(i1); cg[2]=bf16r(i2);
        cg[3]=bf16r(m0*i0); cg[4]=bf16r(m1*i1); cg[5]=bf16r(m2*i2);
        cg[6]=m0*m0*i0 + m1*m1*i1 + m2*m2*i2;
    }
    if (t < 16) {
        float4 c = *(const float4*)(center4 + (gbase + t)*4);
        cS[t*4+0]=c.x; cS[t*4+1]=c.y; cS[t*4+2]=c.z;
        const float* Rp = R12 + (gbase + t)*12;
        #pragma unroll
        for (int r = 0; r < 9; ++r) RS[t*12+r] = Rp[r];
        mfS[t] = mframe[gbase + t];
    }
    nbrS[t] = nbr[gbase*KNN + t];
    __syncthreads();

    {
        int a = t >> 4;
        int j = nbrS[t];
        size_t gj = (size_t)b*NP + j;
        float4 cj = *(const float4*)(center4 + gj*4);
        float dx = bf16r(cj.x - cS[a*4+0]);
        float dy = bf16r(cj.y - cS[a*4+1]);
        float dz = bf16r(cj.z - cS[a*4+2]);
        const float* Rr = RS + a*12;
        float l0 = dx*Rr[0] + dy*Rr[1] + dz*Rr[2];
        float l1 = dx*Rr[3] + dy*Rr[4] + dz*Rr[5];
        float l2 = dx*Rr[6] + dy*Rr[7] + dz*Rr[8];
        float* lp = locS + (size_t)t*5;
        lp[0]=l0; lp[1]=l1; lp[2]=l2;
    }
    float attrk[16];
    {
        int a = t >> 4, d = t & 15;
        #pragma unroll
        for (int k = 0; k < 16; ++k) {
            int j = nbrS[a*16 + k];
            attrk[k] = attr16[((size_t)b*NP + j)*DE + d];
        }
    }
    __syncthreads();

    f32x4 acc0 = {0.f,0.f,0.f,0.f}, acc1 = {0.f,0.f,0.f,0.f};
    int aA = lane & 15, kb = lane >> 4;
    int swzA = (aA & 7) << 3;

    for (int nc = 0; nc < 4; ++nc) {
        {
            const float* lp = locS + (size_t)t*5;
            float l0 = lp[0], l1 = lp[1], l2 = lp[2];
            float s0 = bf16r(l0*l0), s1 = bf16r(l1*l1), s2 = bf16r(l2*l2);
            float b0 = bf16r(l0), b1 = bf16r(l1), b2 = bf16r(l2);
            float* gp = gaussS + (size_t)t*17;
            #pragma unroll
            for (int nl = 0; nl < 16; ++nl) {
                const float* cg = cG + (nc*16 + nl)*8;
                float dotA = s0*cg[0] + s1*cg[1] + s2*cg[2];
                float dotB = b0*cg[3] + b1*cg[4] + b2*cg[5];
                float qv = dotA - 2.f*dotB + cg[6];
                gp[nl] = bf16r(expf(-0.5f*qv));
            }
        }
        __syncthreads();
        {
            int a = t >> 4, d = t & 15;
            const float* gpA = gaussS + (size_t)a*16*17;
            int swzW = (a & 7) << 3;
            #pragma unroll
            for (int nl = 0; nl < 16; ++nl) {
                float acc = 0.f;
                const float* gp = gpA + nl;
                #pragma unroll
                for (int k = 0; k < 16; ++k) acc += gp[k*17] * attrk[k];
                int nd = nl*16 + d;
                ZsU[(a*256 + nd) ^ swzW] = bf16u(acc);
            }
        }
        __syncthreads();
        {
            #pragma unroll
            for (int st = 0; st < 8; ++st) {
                int u0 = (aA*256 + st*32 + kb*8) ^ swzA;
                bf16x8 af = *(const bf16x8*)(&ZsU[u0]);
                int sg = nc*8 + st;
                bf16x8 b0 = ((const bf16x8*)WfF)[((size_t)sg*8 + w*2 + 0)*64 + lane];
                bf16x8 b1 = ((const bf16x8*)WfF)[((size_t)sg*8 + w*2 + 1)*64 + lane];
                acc0 = __builtin_amdgcn_mfma_f32_16x16x32_bf16(af, b0, acc0, 0, 0, 0);
                acc1 = __builtin_amdgcn_mfma_f32_16x16x32_bf16(af, b1, acc1, 0, 0, 0);
            }
        }
        __syncthreads();
    }

    {
        #pragma unroll
        for (int r = 0; r < 4; ++r) {
            int atom = (lane >> 4)*4 + r;
            int swzW = (atom & 7) << 3;
            float v0 = fmaxf(acc0[r], 0.f) * mfS[atom];
            float v1 = fmaxf(acc1[r], 0.f) * mfS[atom];
            int f0 = (w*2 + 0)*16 + (lane & 15);
            int f1 = (w*2 + 1)*16 + (lane & 15);
            yU[(atom*128 + f0) ^ swzW] = bf16u(v0);
            yU[(atom*128 + f1) ^ swzW] = bf16u(v1);
        }
    }
    __syncthreads();

    float* attP = locS;
    if (t < 128) {
        int aq = t & 15, g = t >> 4;
        int swzW = (aq & 7) << 3;
        float s = 0.f;
        #pragma unroll
        for (int cc = 0; cc < 16; ++cc) {
            int c = g*16 + cc;
            unsigned short uv = yU[(aq*128 + c) ^ swzW];
            s += __uint_as_float((unsigned)uv << 16) * bf16r(Watt[c]);
        }
        attP[g*16 + aq] = s;
    }

    f32x4 fa0 = {0.f,0.f,0.f,0.f}, fa1 = {0.f,0.f,0.f,0.f};
    #pragma unroll
    for (int st = 0; st < 4; ++st) {
        int u0 = (aA*128 + st*32 + kb*8) ^ swzA;
        bf16x8 af = *(const bf16x8*)(&yU[u0]);
        bf16x8 b0 = ((const bf16x8*)WfeatF)[((size_t)st*8 + w*2 + 0)*64 + lane];
        bf16x8 b1 = ((const bf16x8*)WfeatF)[((size_t)st*8 + w*2 + 1)*64 + lane];
        fa0 = __builtin_amdgcn_mfma_f32_16x16x32_bf16(af, b0, fa0, 0, 0, 0);
        fa1 = __builtin_amdgcn_mfma_f32_16x16x32_bf16(af, b1, fa1, 0, 0, 0);
    }
    {
        #pragma unroll
        for (int r = 0; r < 4; ++r) {
            int atom = (lane >> 4)*4 + r;
            float m = mfS[atom];
            int f0 = (w*2 + 0)*16 + (lane & 15);
            int f1 = (w*2 + 1)*16 + (lane & 15);
            feat[(gbase + atom)*FF2 + f0] = fa0[r] * m;
            feat[(gbase + atom)*FF2 + f1] = fa1[r] * m;
        }
    }
    __syncthreads();
    if (t < 16) {
        float s = 0.f;
        #pragma unroll
        for (int g = 0; g < 8; ++g) s += attP[g*16 + t];
        att[gbase + t] = s * mfS[t];
    }
}

// ================= K4a =================
__global__ __launch_bounds__(576) void k_start(
    const int* __restrict__ seq_atom, int* __restrict__ start)
{
    int b = blockIdx.x;
    int v = threadIdx.x;
    if (v > NAA) return;
    const int* s = seq_atom + (size_t)b * NP;
    int lo = 0, hi = NP;
    while (lo < hi) {
        int mid = (lo + hi) >> 1;
        if (s[mid] < v) lo = mid + 1; else hi = mid;
    }
    start[b*(NAA+1) + v] = lo;
}

// ================= K4b (identical) =================
__global__ __launch_bounds__(64) void k_pool(
    const int* __restrict__ seq_aa, const int* __restrict__ start,
    const float* __restrict__ att, const float* __restrict__ feat,
    const float* __restrict__ mseq, float* __restrict__ pooled)
{
    __shared__ int   jS[KK2];
    __shared__ int   dS[KK2];
    __shared__ float avS[KK2];
    __shared__ float wS[KK2];
    int blk = blockIdx.x;
    int b = blk >> 9;
    int a = blk & (NAA - 1);
    int t = threadIdx.x;
    if (t == 0) {
        int v = seq_aa[b*NAA + a];
        const int* st = start + b*(NAA+1);
        int cnt = 0;
        for (int d = 0; cnt < KK2 && d < NAA; ++d) {
            int vlo = v - d;
            if (vlo >= 0) {
                int s0 = st[vlo], s1 = st[vlo+1];
                for (int j = s0; j < s1 && cnt < KK2; ++j) { jS[cnt] = j; dS[cnt] = d; ++cnt; }
            }
            int vhi = v + d;
            if (d > 0 && vhi < NAA) {
                int s0 = st[vhi], s1 = st[vhi+1];
                for (int j = s0; j < s1 && cnt < KK2; ++j) { jS[cnt] = j; dS[cnt] = d; ++cnt; }
            }
        }
        float m = -INFINITY;
        for (int k = 0; k < KK2; ++k) {
            float av = att[(size_t)b*NP + jS[k]];
            avS[k] = av;
            m = fmaxf(m, av);
        }
        float ssum = 0.f;
        for (int k = 0; k < KK2; ++k) {
            float g = (dS[k] == 0) ? 1.f : 0.f;
            float w = g * expf(avS[k] - m);
            wS[k] = w;
            ssum += w;
        }
        float inv = 1.f / (ssum + EPSV);
        for (int k = 0; k < KK2; ++k) wS[k] = bf16r(wS[k] * inv);
    }
    __syncthreads();
    int row = b*NAA + a;
    float m = mseq[row];
    for (int ff = t; ff < FF2; ff += 64) {
        float acc = 0.f;
        #pragma unroll
        for (int k = 0; k < KK2; ++k)
            acc += wS[k] * bf16r(feat[((size_t)b*NP + jS[k])*FF2 + ff]);
        pooled[(size_t)row*FF2 + ff] = acc * m;
    }
}

// ================= K5: batchnorm (identical) =================
__global__ __launch_bounds__(128) void k_bnstat1(
    const float* __restrict__ pooled, const float* __restrict__ mseq,
    float* __restrict__ partS, float* __restrict__ partQ)
{
    int g = blockIdx.x, f = threadIdx.x;
    float s = 0.f, q = 0.f;
    for (int r = 0; r < 64; ++r) {
        int row = g*64 + r;
        float m = mseq[row];
        float x = pooled[(size_t)row*FF2 + f];
        s += x*m; q += x*x*m;
    }
    partS[g*FF2 + f] = s;
    partQ[g*FF2 + f] = q;
}

__global__ __launch_bounds__(128) void k_bnstat2(
    const float* __restrict__ partS, const float* __restrict__ partQ,
    const float* __restrict__ mseq,
    const float* __restrict__ gamma, const float* __restrict__ beta,
    float* __restrict__ scaleshift)
{
    __shared__ float msums[128];
    int f = threadIdx.x;
    float mm = 0.f;
    for (int r = f; r < BB*NAA; r += 128) mm += mseq[r];
    msums[f] = mm;
    __syncthreads();
    for (int s = 64; s > 0; s >>= 1) {
        if (f < s) msums[f] += msums[f + s];
        __syncthreads();
    }
    float Sm = msums[0];
    float msum = Sm + EPSV;
    float s = 0.f, q = 0.f;
    for (int g = 0; g < 64; ++g) { s += partS[g*FF2 + f]; q += partQ[g*FF2 + f]; }
    float mean = s / msum;
    float var = (q - 2.f*mean*s + mean*mean*Sm) / msum;
    float rstd = 1.f / sqrtf(var + 1e-5f);
    float sc = rstd * gamma[f];
    scaleshift[f] = sc;
    scaleshift[FF2 + f] = beta[f] - mean*sc;
}

__global__ __launch_bounds__(256) void k_bnapply(
    const float* __restrict__ pooled, const float* __restrict__ scaleshift,
    const float* __restrict__ mseq, float* __restrict__ out)
{
    int idx = blockIdx.x*256 + threadIdx.x;
    if (idx < BB*NAA*FF2) {
        int f = idx & (FF2 - 1);
        int row = idx >> 7;
        float v = pooled[idx]*scaleshift[f] + scaleshift[FF2 + f];
        v = v > 0.f ? v : 0.f;
        out[idx] = v * mseq[row];
    }
    if (idx < BB*NAA) out[BB*NAA*FF2 + idx] = mseq[idx];
}

// ================= launch =================
extern "C" void kernel_launch(void* const* d_in, const int* in_sizes, int n_in,
                              void* d_out, int out_size, void* d_ws, size_t ws_size,
                              hipStream_t stream)
{
    const int*   fidx   = (const int*)  d_in[0];
    const int*   aidx   = (const int*)  d_in[1];
    const int*   seqat  = (const int*)  d_in[2];
    const int*   seqaa  = (const int*)  d_in[3];
    const float* pc     = (const float*)d_in[4];
    const float* mframe = (const float*)d_in[5];
    const float* mseq   = (const float*)d_in[6];
    const float* emb    = (const float*)d_in[7];
    const float* gmu    = (const float*)d_in[8];
    const float* gsig   = (const float*)d_in[9];
    const float* Wf     = (const float*)d_in[10];
    const float* Watt   = (const float*)d_in[11];
    const float* Wfeat  = (const float*)d_in[12];
    const float* gamma  = (const float*)d_in[13];
    const float* beta   = (const float*)d_in[14];

    char* ws = (char*)d_ws;
    float* center4 = (float*)(ws + OFF_CENTER);
    float* R12     = (float*)(ws + OFF_R);
    float* attr16  = (float*)(ws + OFF_ATTR);
    int*   nbr     = (int*)  (ws + OFF_NBR);
    float* att     = (float*)(ws + OFF_ATT);
    float* feat    = (float*)(ws + OFF_FEAT);
    float* pooled  = (float*)(ws + OFF_POOLED);
    unsigned short* WfF    = (unsigned short*)(ws + OFF_WFFRAG);
    unsigned short* WfeatF = (unsigned short*)(ws + OFF_WFEATFRAG);
    int*   start   = (int*)  (ws + OFF_START);
    float* partS   = (float*)(ws + OFF_PARTS);
    float* partQ   = (float*)(ws + OFF_PARTQ);
    float* ss      = (float*)(ws + OFF_SS);
    float* outp    = (float*)d_out;

    hipLaunchKernelGGL(k_prep, dim3(576), dim3(256), 0, stream,
                       Wf, Wfeat, WfF, WfeatF);
    hipLaunchKernelGGL(k_frames, dim3(64), dim3(256), 0, stream,
                       fidx, aidx, pc, mframe, emb, center4, R12, attr16);
    hipLaunchKernelGGL(k_knn, dim3(2048), dim3(256), 0, stream, center4, nbr);
    hipLaunchKernelGGL(k_filter, dim3(1024), dim3(256), 0, stream,
                       center4, R12, attr16, nbr, mframe, gmu, gsig,
                       WfF, Watt, WfeatF, att, feat);
    hipLaunchKernelGGL(k_start, dim3(BB), dim3(576), 0, stream, seqat, start);
    hipLaunchKernelGGL(k_pool, dim3(BB*NAA), dim3(64), 0, stream,
                       seqaa, start, att, feat, mseq, pooled);
    hipLaunchKernelGGL(k_bnstat1, dim3(64), dim3(128), 0, stream,
                       pooled, mseq, partS, partQ);
    hipLaunchKernelGGL(k_bnstat2, dim3(1), dim3(128), 0, stream,
                       partS, partQ, mseq, gamma, beta, ss);
    hipLaunchKernelGGL(k_bnapply, dim3((BB*NAA*FF2 + 255)/256), dim3(256), 0, stream,
                       pooled, ss, mseq, outp);
}

// Round 18
// 124.783 us; speedup vs baseline: 1.3322x; 1.3322x over previous
//
#include <hip/hip_runtime.h>
#include <math.h>

#define BB 8
#define NP 2048
#define NAA 512
#define KNN 16
#define KK2 14
#define DE 16
#define NG 64
#define FF 128
#define FF2 128
#define NCAT 39
#define EPSV 1e-6f

typedef __attribute__((ext_vector_type(8))) short bf16x8;
typedef __attribute__((ext_vector_type(4))) float f32x4;

// round-to-nearest-even f32 -> bf16 value (kept in f32)
__device__ __forceinline__ float bf16r(float x) {
    unsigned u = __float_as_uint(x);
    u = u + 0x7FFFu + ((u >> 16) & 1u);
    return __uint_as_float(u & 0xFFFF0000u);
}
__device__ __forceinline__ unsigned short bf16u(float x) {
    unsigned u = __float_as_uint(x);
    u = u + 0x7FFFu + ((u >> 16) & 1u);
    return (unsigned short)(u >> 16);
}

// ---------------- workspace layout (bytes) ----------------
#define OFF_CENTER   0u
#define OFF_R        262144u
#define OFF_ATTR     1048576u
#define OFF_NBR      2097152u
#define OFF_ATT      3145728u
#define OFF_FEAT     3211264u
#define OFF_POOLED   11599872u
#define OFF_WFFRAG   (OFF_POOLED)
#define OFF_WFEATFRAG (OFF_POOLED + 262144u)
#define OFF_START    13697024u
#define OFF_PARTS    13713536u
#define OFF_PARTQ    13746304u
#define OFF_SS       13779072u

// ================= K0: pack W_filter / W_feat into MFMA B-fragment order ===
__global__ __launch_bounds__(256) void k_prep(
    const float* __restrict__ Wf, const float* __restrict__ Wfeat,
    unsigned short* __restrict__ WfF, unsigned short* __restrict__ WfeatF)
{
    int id = blockIdx.x * 256 + threadIdx.x;
    if (id < 32*8*64*8) {
        int i = id & 7, l = (id >> 3) & 63, nt = (id >> 9) & 7, s = id >> 12;
        int row = s*32 + (l >> 4)*8 + i;
        int col = nt*16 + (l & 15);
        WfF[id] = bf16u(Wf[(size_t)row*FF + col]);
    } else {
        int id2 = id - 32*8*64*8;
        if (id2 < 4*8*64*8) {
            int i = id2 & 7, l = (id2 >> 3) & 63, nt = (id2 >> 9) & 7, s = id2 >> 12;
            int row = s*32 + (l >> 4)*8 + i;
            int col = nt*16 + (l & 15);
            WfeatF[id2] = bf16u(Wfeat[(size_t)row*FF2 + col]);
        }
    }
}

// ================= K1: frames + attr (identical) =================
__global__ __launch_bounds__(256) void k_frames(
    const int* __restrict__ fidx, const int* __restrict__ aidx,
    const float* __restrict__ pc, const float* __restrict__ mframe,
    const float* __restrict__ emb,
    float* __restrict__ center4, float* __restrict__ R12, float* __restrict__ attr16)
{
    int t = blockIdx.x * 256 + threadIdx.x;
    if (t >= BB * NP) return;
    int b = t / NP;
    const float* pcb = pc + (size_t)b * NP * 3;
    int i0 = fidx[t*3+0], i1 = fidx[t*3+1], i2 = fidx[t*3+2];
    float cx = pcb[i0*3+0], cy = pcb[i0*3+1], cz = pcb[i0*3+2];
    float ax = pcb[i1*3+0]-cx, ay = pcb[i1*3+1]-cy, az = pcb[i1*3+2]-cz;
    float bx = pcb[i2*3+0]-cx, by = pcb[i2*3+1]-cy, bz = pcb[i2*3+2]-cz;
    float n1 = sqrtf(ax*ax + ay*ay + az*az) + EPSV;
    float e1x = ax/n1, e1y = ay/n1, e1z = az/n1;
    float nx = ay*bz - az*by;
    float ny = az*bx - ax*bz;
    float nz = ax*by - ay*bx;
    float n3 = sqrtf(nx*nx + ny*ny + nz*nz) + EPSV;
    float e3x = nx/n3, e3y = ny/n3, e3z = nz/n3;
    float e2x = e3y*e1z - e3z*e1y;
    float e2y = e3z*e1x - e3x*e1z;
    float e2z = e3x*e1y - e3y*e1x;

    float4 c4; c4.x = cx; c4.y = cy; c4.z = cz; c4.w = 0.f;
    *(float4*)(center4 + (size_t)t*4) = c4;
    float* Rp = R12 + (size_t)t*12;
    Rp[0]=bf16r(e1x); Rp[1]=bf16r(e1y); Rp[2]=bf16r(e1z);
    Rp[3]=bf16r(e2x); Rp[4]=bf16r(e2y); Rp[5]=bf16r(e2z);
    Rp[6]=bf16r(e3x); Rp[7]=bf16r(e3y); Rp[8]=bf16r(e3z);

    int ai = aidx[t];
    float m = mframe[t];
    const float* er = emb + (size_t)ai * DE;
    float* ap = attr16 + (size_t)t * DE;
    #pragma unroll
    for (int d = 0; d < DE; ++d) ap[d] = bf16r(er[d] * m);
}

// ================= K2: KNN top-16 — LDS scan, cheap chains, 5 blocks/CU ====
// R14 structure (float4 LDS reads, NO stagger, immediate offsets). Pass A:
// 4 independent 2-deep min/max chains (parity elements of each float4);
// per-thread merge of 8 kept -> 4 smallest (any subset keeps T' a valid
// upper bound on the true 16th). T' = 16th of 16x4 kept. Pass B: gather
// {j : d2 <= T'} with exact rn d2; final exact (d2,idx) sort -> selection
// bit-identical. LDS 32384 B -> 5 blocks/CU.
__global__ __launch_bounds__(256) void k_knn(
    const float* __restrict__ center4, int* __restrict__ nbr)
{
    __shared__ __align__(16) float sx[NP], sy[NP], sz[NP];   // 24576 B
    __shared__ unsigned long long lists[16*60];              // 7680 B (aliases kbufA 4096 B)
    __shared__ int cntS[16];
    __shared__ unsigned int TqU[16];
    unsigned int* kbufA = (unsigned int*)lists;              // [4][256]

    int b = blockIdx.x >> 7;
    int qchunk = blockIdx.x & 127;
    int t = threadIdx.x;
    const float* cb = center4 + (size_t)b * NP * 4;
    for (int j = t; j < NP; j += 256) {
        float4 c = *(const float4*)(cb + (size_t)j*4);
        sx[j] = c.x; sy[j] = c.y; sz[j] = c.z;
    }
    __syncthreads();

    int qloc = t & 15, split = t >> 4;               // 16 splits x 128 cand
    int q = qchunk * 16 + qloc;
    float qx = sx[q], qy = sy[q], qz = sz[q];
    int j0 = split * 128;

    // ---- pass A: 4 independent 2-deep chains, static offsets
    unsigned int e0a = ~0u, e1a = ~0u;
    unsigned int e0b = ~0u, e1b = ~0u;
    unsigned int e0c = ~0u, e1c = ~0u;
    unsigned int e0d = ~0u, e1d = ~0u;
    for (int jj = 0; jj < 128; jj += 4) {
        int j = j0 + jj;
        float4 x4 = *(const float4*)(&sx[j]);
        float4 y4 = *(const float4*)(&sy[j]);
        float4 z4 = *(const float4*)(&sz[j]);
        float dx0 = __fsub_rn(qx, x4.x), dy0 = __fsub_rn(qy, y4.x), dz0 = __fsub_rn(qz, z4.x);
        float dx1 = __fsub_rn(qx, x4.y), dy1 = __fsub_rn(qy, y4.y), dz1 = __fsub_rn(qz, z4.y);
        float dx2 = __fsub_rn(qx, x4.z), dy2 = __fsub_rn(qy, y4.z), dz2 = __fsub_rn(qz, z4.z);
        float dx3 = __fsub_rn(qx, x4.w), dy3 = __fsub_rn(qy, y4.w), dz3 = __fsub_rn(qz, z4.w);
        unsigned c0 = __float_as_uint(__fadd_rn(__fadd_rn(__fmul_rn(dx0,dx0), __fmul_rn(dy0,dy0)), __fmul_rn(dz0,dz0)));
        unsigned c1 = __float_as_uint(__fadd_rn(__fadd_rn(__fmul_rn(dx1,dx1), __fmul_rn(dy1,dy1)), __fmul_rn(dz1,dz1)));
        unsigned c2 = __float_as_uint(__fadd_rn(__fadd_rn(__fmul_rn(dx2,dx2), __fmul_rn(dy2,dy2)), __fmul_rn(dz2,dz2)));
        unsigned c3 = __float_as_uint(__fadd_rn(__fadd_rn(__fmul_rn(dx3,dx3), __fmul_rn(dy3,dy3)), __fmul_rn(dz3,dz3)));
        unsigned n1;
        n1 = max(e0a, min(e1a, c0)); e0a = min(e0a, c0); e1a = n1;
        n1 = max(e0b, min(e1b, c1)); e0b = min(e0b, c1); e1b = n1;
        n1 = max(e0c, min(e1c, c2)); e0c = min(e0c, c2); e1c = n1;
        n1 = max(e0d, min(e1d, c3)); e0d = min(e0d, c3); e1d = n1;
    }
    // ---- per-thread merge: 4 smallest of the 8 kept (sorted 4-ladder)
    {
        unsigned m0 = ~0u, m1 = ~0u, m2 = ~0u, m3 = ~0u;
        unsigned vals[8] = {e0a, e1a, e0b, e1b, e0c, e1c, e0d, e1d};
        #pragma unroll
        for (int i = 0; i < 8; ++i) {
            unsigned c = vals[i];
            unsigned n0 = min(m0, c);
            unsigned n1 = max(m0, min(m1, c));
            unsigned n2 = max(m1, min(m2, c));
            unsigned n3 = max(m2, min(m3, c));
            m0 = n0; m1 = n1; m2 = n2; m3 = n3;
        }
        kbufA[0*256 + t] = m0;
        kbufA[1*256 + t] = m1;
        kbufA[2*256 + t] = m2;
        kbufA[3*256 + t] = m3;
    }
    __syncthreads();

    // ---- merge: T' = 16th smallest of 16 splits x 4 kept
    if (t < 16) {
        unsigned int arr[16];
        #pragma unroll
        for (int s = 0; s < 16; ++s) arr[s] = ~0u;
        for (int sp = 0; sp < 16; ++sp) {
            int lidx = sp*16 + t;
            #pragma unroll
            for (int s = 0; s < 4; ++s) {
                unsigned int v = kbufA[s*256 + lidx];
                if (v >= arr[15]) break;             // per-split sorted ascending
                unsigned int c = v;
                #pragma unroll
                for (int u = 0; u < 16; ++u) {
                    unsigned int lo = min(c, arr[u]), hi = max(c, arr[u]);
                    arr[u] = lo; c = hi;
                }
            }
        }
        TqU[t] = arr[15];
        cntS[t] = 0;
    }
    __syncthreads();       // merge done -> kbufA dead -> lists reuse OK
    unsigned int T = TqU[qloc];

    // ---- pass B: gather all candidates with d2 <= T' (exact formula)
    for (int jj = 0; jj < 128; jj += 4) {
        int j = j0 + jj;
        float4 x4 = *(const float4*)(&sx[j]);
        float4 y4 = *(const float4*)(&sy[j]);
        float4 z4 = *(const float4*)(&sz[j]);
        #pragma unroll
        for (int c4i = 0; c4i < 4; ++c4i) {
            float xx = c4i==0?x4.x:c4i==1?x4.y:c4i==2?x4.z:x4.w;
            float yy = c4i==0?y4.x:c4i==1?y4.y:c4i==2?y4.z:y4.w;
            float zz = c4i==0?z4.x:c4i==1?z4.y:c4i==2?z4.z:z4.w;
            float dx = __fsub_rn(qx, xx);
            float dy = __fsub_rn(qy, yy);
            float dz = __fsub_rn(qz, zz);
            float d2 = __fadd_rn(__fadd_rn(__fmul_rn(dx,dx), __fmul_rn(dy,dy)), __fmul_rn(dz,dz));
            unsigned int db = __float_as_uint(d2);
            if (db <= T) {
                int slot = atomicAdd(&cntS[qloc], 1);
                if (slot < 60)
                    lists[qloc*60 + slot] = ((unsigned long long)db << 32) | (unsigned)(j + c4i);
            }
        }
    }
    __syncthreads();

    // ---- final: exact (d2, idx) top-16 of gathered (lower-index ties)
    if (t < 16) {
        int n = cntS[t] < 60 ? cntS[t] : 60;
        unsigned long long arr[16];
        #pragma unroll
        for (int s = 0; s < 16; ++s) arr[s] = ~0ULL;
        for (int i = 0; i < n; ++i) {
            unsigned long long key = lists[t*60 + i];
            if (key < arr[15]) {
                unsigned long long c = key;
                #pragma unroll
                for (int u = 0; u < 16; ++u) {
                    unsigned long long lo = c < arr[u] ? c : arr[u];
                    unsigned long long hi = c < arr[u] ? arr[u] : c;
                    arr[u] = lo; c = hi;
                }
            }
        }
        int qg = qchunk * 16 + t;
        int* outp = nbr + ((size_t)b*NP + qg) * KNN;
        #pragma unroll
        for (int s = 0; s < 16; ++s) outp[s] = (int)(arr[s] & 0xFFFFFFFFu);
    }
}

// ================= K3: gauss filter + MFMA y/feat (identical) =======
__global__ __launch_bounds__(256) void k_filter(
    const float* __restrict__ center4, const float* __restrict__ R12,
    const float* __restrict__ attr16, const int* __restrict__ nbr,
    const float* __restrict__ mframe,
    const float* __restrict__ mu, const float* __restrict__ sigma,
    const unsigned short* __restrict__ WfF, const float* __restrict__ Watt,
    const unsigned short* __restrict__ WfeatF,
    float* __restrict__ att, float* __restrict__ feat)
{
    __shared__ float cG[NG*8];
    __shared__ float locS[256*5];
    __shared__ float gaussS[256*17];
    __shared__ __align__(16) unsigned short ZsU[16*256];
    __shared__ __align__(16) unsigned short yU[16*128];
    __shared__ float cS[16*4];
    __shared__ float RS[16*12];
    __shared__ int   nbrS[256];
    __shared__ float mfS[16];

    int t = threadIdx.x;
    int lane = t & 63, w = t >> 6;
    int blk = blockIdx.x;
    int b = blk / (NP/16);
    int abase = (blk % (NP/16)) * 16;
    size_t gbase = (size_t)b * NP + abase;

    if (t < NG) {
        float s0 = sigma[t*3+0], s1 = sigma[t*3+1], s2 = sigma[t*3+2];
        float i0 = 1.f/(s0*s0 + EPSV), i1 = 1.f/(s1*s1 + EPSV), i2 = 1.f/(s2*s2 + EPSV);
        float m0 = mu[t*3+0], m1 = mu[t*3+1], m2 = mu[t*3+2];
        float* cg = cG + t*8;
        cg[0]=bf16r(i0); cg[1]=bf16r(i1); cg[2]=bf16r(i2);
        cg[3]=bf16r(m0*i0); cg[4]=bf16r(m1*i1); cg[5]=bf16r(m2*i2);
        cg[6]=m0*m0*i0 + m1*m1*i1 + m2*m2*i2;
    }
    if (t < 16) {
        float4 c = *(const float4*)(center4 + (gbase + t)*4);
        cS[t*4+0]=c.x; cS[t*4+1]=c.y; cS[t*4+2]=c.z;
        const float* Rp = R12 + (gbase + t)*12;
        #pragma unroll
        for (int r = 0; r < 9; ++r) RS[t*12+r] = Rp[r];
        mfS[t] = mframe[gbase + t];
    }
    nbrS[t] = nbr[gbase*KNN + t];
    __syncthreads();

    {
        int a = t >> 4;
        int j = nbrS[t];
        size_t gj = (size_t)b*NP + j;
        float4 cj = *(const float4*)(center4 + gj*4);
        float dx = bf16r(cj.x - cS[a*4+0]);
        float dy = bf16r(cj.y - cS[a*4+1]);
        float dz = bf16r(cj.z - cS[a*4+2]);
        const float* Rr = RS + a*12;
        float l0 = dx*Rr[0] + dy*Rr[1] + dz*Rr[2];
        float l1 = dx*Rr[3] + dy*Rr[4] + dz*Rr[5];
        float l2 = dx*Rr[6] + dy*Rr[7] + dz*Rr[8];
        float* lp = locS + (size_t)t*5;
        lp[0]=l0; lp[1]=l1; lp[2]=l2;
    }
    float attrk[16];
    {
        int a = t >> 4, d = t & 15;
        #pragma unroll
        for (int k = 0; k < 16; ++k) {
            int j = nbrS[a*16 + k];
            attrk[k] = attr16[((size_t)b*NP + j)*DE + d];
        }
    }
    __syncthreads();

    f32x4 acc0 = {0.f,0.f,0.f,0.f}, acc1 = {0.f,0.f,0.f,0.f};
    int aA = lane & 15, kb = lane >> 4;
    int swzA = (aA & 7) << 3;

    for (int nc = 0; nc < 4; ++nc) {
        {
            const float* lp = locS + (size_t)t*5;
            float l0 = lp[0], l1 = lp[1], l2 = lp[2];
            float s0 = bf16r(l0*l0), s1 = bf16r(l1*l1), s2 = bf16r(l2*l2);
            float b0 = bf16r(l0), b1 = bf16r(l1), b2 = bf16r(l2);
            float* gp = gaussS + (size_t)t*17;
            #pragma unroll
            for (int nl = 0; nl < 16; ++nl) {
                const float* cg = cG + (nc*16 + nl)*8;
                float dotA = s0*cg[0] + s1*cg[1] + s2*cg[2];
                float dotB = b0*cg[3] + b1*cg[4] + b2*cg[5];
                float qv = dotA - 2.f*dotB + cg[6];
                gp[nl] = bf16r(expf(-0.5f*qv));
            }
        }
        __syncthreads();
        {
            int a = t >> 4, d = t & 15;
            const float* gpA = gaussS + (size_t)a*16*17;
            int swzW = (a & 7) << 3;
            #pragma unroll
            for (int nl = 0; nl < 16; ++nl) {
                float acc = 0.f;
                const float* gp = gpA + nl;
                #pragma unroll
                for (int k = 0; k < 16; ++k) acc += gp[k*17] * attrk[k];
                int nd = nl*16 + d;
                ZsU[(a*256 + nd) ^ swzW] = bf16u(acc);
            }
        }
        __syncthreads();
        {
            #pragma unroll
            for (int st = 0; st < 8; ++st) {
                int u0 = (aA*256 + st*32 + kb*8) ^ swzA;
                bf16x8 af = *(const bf16x8*)(&ZsU[u0]);
                int sg = nc*8 + st;
                bf16x8 b0 = ((const bf16x8*)WfF)[((size_t)sg*8 + w*2 + 0)*64 + lane];
                bf16x8 b1 = ((const bf16x8*)WfF)[((size_t)sg*8 + w*2 + 1)*64 + lane];
                acc0 = __builtin_amdgcn_mfma_f32_16x16x32_bf16(af, b0, acc0, 0, 0, 0);
                acc1 = __builtin_amdgcn_mfma_f32_16x16x32_bf16(af, b1, acc1, 0, 0, 0);
            }
        }
        __syncthreads();
    }

    {
        #pragma unroll
        for (int r = 0; r < 4; ++r) {
            int atom = (lane >> 4)*4 + r;
            int swzW = (atom & 7) << 3;
            float v0 = fmaxf(acc0[r], 0.f) * mfS[atom];
            float v1 = fmaxf(acc1[r], 0.f) * mfS[atom];
            int f0 = (w*2 + 0)*16 + (lane & 15);
            int f1 = (w*2 + 1)*16 + (lane & 15);
            yU[(atom*128 + f0) ^ swzW] = bf16u(v0);
            yU[(atom*128 + f1) ^ swzW] = bf16u(v1);
        }
    }
    __syncthreads();

    float* attP = locS;
    if (t < 128) {
        int aq = t & 15, g = t >> 4;
        int swzW = (aq & 7) << 3;
        float s = 0.f;
        #pragma unroll
        for (int cc = 0; cc < 16; ++cc) {
            int c = g*16 + cc;
            unsigned short uv = yU[(aq*128 + c) ^ swzW];
            s += __uint_as_float((unsigned)uv << 16) * bf16r(Watt[c]);
        }
        attP[g*16 + aq] = s;
    }

    f32x4 fa0 = {0.f,0.f,0.f,0.f}, fa1 = {0.f,0.f,0.f,0.f};
    #pragma unroll
    for (int st = 0; st < 4; ++st) {
        int u0 = (aA*128 + st*32 + kb*8) ^ swzA;
        bf16x8 af = *(const bf16x8*)(&yU[u0]);
        bf16x8 b0 = ((const bf16x8*)WfeatF)[((size_t)st*8 + w*2 + 0)*64 + lane];
        bf16x8 b1 = ((const bf16x8*)WfeatF)[((size_t)st*8 + w*2 + 1)*64 + lane];
        fa0 = __builtin_amdgcn_mfma_f32_16x16x32_bf16(af, b0, fa0, 0, 0, 0);
        fa1 = __builtin_amdgcn_mfma_f32_16x16x32_bf16(af, b1, fa1, 0, 0, 0);
    }
    {
        #pragma unroll
        for (int r = 0; r < 4; ++r) {
            int atom = (lane >> 4)*4 + r;
            float m = mfS[atom];
            int f0 = (w*2 + 0)*16 + (lane & 15);
            int f1 = (w*2 + 1)*16 + (lane & 15);
            feat[(gbase + atom)*FF2 + f0] = fa0[r] * m;
            feat[(gbase + atom)*FF2 + f1] = fa1[r] * m;
        }
    }
    __syncthreads();
    if (t < 16) {
        float s = 0.f;
        #pragma unroll
        for (int g = 0; g < 8; ++g) s += attP[g*16 + t];
        att[gbase + t] = s * mfS[t];
    }
}

// ================= K4a =================
__global__ __launch_bounds__(576) void k_start(
    const int* __restrict__ seq_atom, int* __restrict__ start)
{
    int b = blockIdx.x;
    int v = threadIdx.x;
    if (v > NAA) return;
    const int* s = seq_atom + (size_t)b * NP;
    int lo = 0, hi = NP;
    while (lo < hi) {
        int mid = (lo + hi) >> 1;
        if (s[mid] < v) lo = mid + 1; else hi = mid;
    }
    start[b*(NAA+1) + v] = lo;
}

// ================= K4b (identical) =================
__global__ __launch_bounds__(64) void k_pool(
    const int* __restrict__ seq_aa, const int* __restrict__ start,
    const float* __restrict__ att, const float* __restrict__ feat,
    const float* __restrict__ mseq, float* __restrict__ pooled)
{
    __shared__ int   jS[KK2];
    __shared__ int   dS[KK2];
    __shared__ float avS[KK2];
    __shared__ float wS[KK2];
    int blk = blockIdx.x;
    int b = blk >> 9;
    int a = blk & (NAA - 1);
    int t = threadIdx.x;
    if (t == 0) {
        int v = seq_aa[b*NAA + a];
        const int* st = start + b*(NAA+1);
        int cnt = 0;
        for (int d = 0; cnt < KK2 && d < NAA; ++d) {
            int vlo = v - d;
            if (vlo >= 0) {
                int s0 = st[vlo], s1 = st[vlo+1];
                for (int j = s0; j < s1 && cnt < KK2; ++j) { jS[cnt] = j; dS[cnt] = d; ++cnt; }
            }
            int vhi = v + d;
            if (d > 0 && vhi < NAA) {
                int s0 = st[vhi], s1 = st[vhi+1];
                for (int j = s0; j < s1 && cnt < KK2; ++j) { jS[cnt] = j; dS[cnt] = d; ++cnt; }
            }
        }
        float m = -INFINITY;
        for (int k = 0; k < KK2; ++k) {
            float av = att[(size_t)b*NP + jS[k]];
            avS[k] = av;
            m = fmaxf(m, av);
        }
        float ssum = 0.f;
        for (int k = 0; k < KK2; ++k) {
            float g = (dS[k] == 0) ? 1.f : 0.f;
            float w = g * expf(avS[k] - m);
            wS[k] = w;
            ssum += w;
        }
        float inv = 1.f / (ssum + EPSV);
        for (int k = 0; k < KK2; ++k) wS[k] = bf16r(wS[k] * inv);
    }
    __syncthreads();
    int row = b*NAA + a;
    float m = mseq[row];
    for (int ff = t; ff < FF2; ff += 64) {
        float acc = 0.f;
        #pragma unroll
        for (int k = 0; k < KK2; ++k)
            acc += wS[k] * bf16r(feat[((size_t)b*NP + jS[k])*FF2 + ff]);
        pooled[(size_t)row*FF2 + ff] = acc * m;
    }
}

// ================= K5: batchnorm (identical) =================
__global__ __launch_bounds__(128) void k_bnstat1(
    const float* __restrict__ pooled, const float* __restrict__ mseq,
    float* __restrict__ partS, float* __restrict__ partQ)
{
    int g = blockIdx.x, f = threadIdx.x;
    float s = 0.f, q = 0.f;
    for (int r = 0; r < 64; ++r) {
        int row = g*64 + r;
        float m = mseq[row];
        float x = pooled[(size_t)row*FF2 + f];
        s += x*m; q += x*x*m;
    }
    partS[g*FF2 + f] = s;
    partQ[g*FF2 + f] = q;
}

__global__ __launch_bounds__(128) void k_bnstat2(
    const float* __restrict__ partS, const float* __restrict__ partQ,
    const float* __restrict__ mseq,
    const float* __restrict__ gamma, const float* __restrict__ beta,
    float* __restrict__ scaleshift)
{
    __shared__ float msums[128];
    int f = threadIdx.x;
    float mm = 0.f;
    for (int r = f; r < BB*NAA; r += 128) mm += mseq[r];
    msums[f] = mm;
    __syncthreads();
    for (int s = 64; s > 0; s >>= 1) {
        if (f < s) msums[f] += msums[f + s];
        __syncthreads();
    }
    float Sm = msums[0];
    float msum = Sm + EPSV;
    float s = 0.f, q = 0.f;
    for (int g = 0; g < 64; ++g) { s += partS[g*FF2 + f]; q += partQ[g*FF2 + f]; }
    float mean = s / msum;
    float var = (q - 2.f*mean*s + mean*mean*Sm) / msum;
    float rstd = 1.f / sqrtf(var + 1e-5f);
    float sc = rstd * gamma[f];
    scaleshift[f] = sc;
    scaleshift[FF2 + f] = beta[f] - mean*sc;
}

__global__ __launch_bounds__(256) void k_bnapply(
    const float* __restrict__ pooled, const float* __restrict__ scaleshift,
    const float* __restrict__ mseq, float* __restrict__ out)
{
    int idx = blockIdx.x*256 + threadIdx.x;
    if (idx < BB*NAA*FF2) {
        int f = idx & (FF2 - 1);
        int row = idx >> 7;
        float v = pooled[idx]*scaleshift[f] + scaleshift[FF2 + f];
        v = v > 0.f ? v : 0.f;
        out[idx] = v * mseq[row];
    }
    if (idx < BB*NAA) out[BB*NAA*FF2 + idx] = mseq[idx];
}

// ================= launch =================
extern "C" void kernel_launch(void* const* d_in, const int* in_sizes, int n_in,
                              void* d_out, int out_size, void* d_ws, size_t ws_size,
                              hipStream_t stream)
{
    const int*   fidx   = (const int*)  d_in[0];
    const int*   aidx   = (const int*)  d_in[1];
    const int*   seqat  = (const int*)  d_in[2];
    const int*   seqaa  = (const int*)  d_in[3];
    const float* pc     = (const float*)d_in[4];
    const float* mframe = (const float*)d_in[5];
    const float* mseq   = (const float*)d_in[6];
    const float* emb    = (const float*)d_in[7];
    const float* gmu    = (const float*)d_in[8];
    const float* gsig   = (const float*)d_in[9];
    const float* Wf     = (const float*)d_in[10];
    const float* Watt   = (const float*)d_in[11];
    const float* Wfeat  = (const float*)d_in[12];
    const float* gamma  = (const float*)d_in[13];
    const float* beta   = (const float*)d_in[14];

    char* ws = (char*)d_ws;
    float* center4 = (float*)(ws + OFF_CENTER);
    float* R12     = (float*)(ws + OFF_R);
    float* attr16  = (float*)(ws + OFF_ATTR);
    int*   nbr     = (int*)  (ws + OFF_NBR);
    float* att     = (float*)(ws + OFF_ATT);
    float* feat    = (float*)(ws + OFF_FEAT);
    float* pooled  = (float*)(ws + OFF_POOLED);
    unsigned short* WfF    = (unsigned short*)(ws + OFF_WFFRAG);
    unsigned short* WfeatF = (unsigned short*)(ws + OFF_WFEATFRAG);
    int*   start   = (int*)  (ws + OFF_START);
    float* partS   = (float*)(ws + OFF_PARTS);
    float* partQ   = (float*)(ws + OFF_PARTQ);
    float* ss      = (float*)(ws + OFF_SS);
    float* outp    = (float*)d_out;

    hipLaunchKernelGGL(k_prep, dim3(576), dim3(256), 0, stream,
                       Wf, Wfeat, WfF, WfeatF);
    hipLaunchKernelGGL(k_frames, dim3(64), dim3(256), 0, stream,
                       fidx, aidx, pc, mframe, emb, center4, R12, attr16);
    hipLaunchKernelGGL(k_knn, dim3(1024), dim3(256), 0, stream, center4, nbr);
    hipLaunchKernelGGL(k_filter, dim3(1024), dim3(256), 0, stream,
                       center4, R12, attr16, nbr, mframe, gmu, gsig,
                       WfF, Watt, WfeatF, att, feat);
    hipLaunchKernelGGL(k_start, dim3(BB), dim3(576), 0, stream, seqat, start);
    hipLaunchKernelGGL(k_pool, dim3(BB*NAA), dim3(64), 0, stream,
                       seqaa, start, att, feat, mseq, pooled);
    hipLaunchKernelGGL(k_bnstat1, dim3(64), dim3(128), 0, stream,
                       pooled, mseq, partS, partQ);
    hipLaunchKernelGGL(k_bnstat2, dim3(1), dim3(128), 0, stream,
                       partS, partQ, mseq, gamma, beta, ss);
    hipLaunchKernelGGL(k_bnapply, dim3((BB*NAA*FF2 + 255)/256), dim3(256), 0, stream,
                       pooled, ss, mseq, outp);
}